// Round 1
// baseline (1884.566 us; speedup 1.0000x reference)
//
#include <hip/hip_runtime.h>

#define NN     100000
#define EE     3200000
#define NF     512
#define HIDN   64
#define NCLS   64
#define ALPHA  0.1f

#define CHUNK  512                      // elements per scan block
#define NB     196                      // ceil(NN / CHUNK)

#define SC_BLOCKS 2048                  // persistent scatter grid: 256 CU x 8 blk
                                        // (co-resident => blockIdx%8 -> XCD holds)

typedef unsigned short ushort_t;
typedef unsigned int   uint_t;

__device__ inline ushort_t f2bf(float f)   // fp32 -> bf16 RTN-even
{
    uint_t u = __float_as_uint(f);
    u += 0x7FFFu + ((u >> 16) & 1u);
    return (ushort_t)(u >> 16);
}
__device__ inline float bf2f(ushort_t b)
{
    return __uint_as_float(((uint_t)b) << 16);
}

// non-temporal 8B edge load (csr is a 25.6MB stream re-read each iteration;
// keep it out of L2 so the 12.8MB gather table stays resident)
__device__ inline int2 ldnt_e(const int2* p)
{
    unsigned long long v =
        __builtin_nontemporal_load((const unsigned long long*)p);
    int2 r;
    r.x = (int)(v & 0xFFFFFFFFull);
    r.y = (int)(v >> 32);
    return r;
}

// ---------------------------------------------------------------------------
// Tiled fp32 GEMM: C[nrows x 64] = act(A[nrows x K] @ B[K x 64])  (fp32 out)
// ---------------------------------------------------------------------------
template <bool RELU>
__global__ __launch_bounds__(256) void gemm_kernel(
    const float* __restrict__ A, const float* __restrict__ B,
    float* __restrict__ C, int nrows, int K)
{
    const int BK = 16;
    __shared__ float AsT[BK][68];
    __shared__ float Bs [BK][68];

    int tid = threadIdx.x;
    int tx  = tid & 15;
    int ty  = tid >> 4;
    int rowBase = blockIdx.x * 64;

    int arow = tid >> 2;
    int ak   = (tid & 3) * 4;
    int brow = tid >> 4;
    int bcol = (tid & 15) * 4;

    float acc[4][4] = {};

    for (int k0 = 0; k0 < K; k0 += BK) {
        float4 av;
        int gr = rowBase + arow;
        if (gr < nrows) av = *(const float4*)(A + (size_t)gr * K + k0 + ak);
        else            av = make_float4(0.f, 0.f, 0.f, 0.f);
        float4 bv = *(const float4*)(B + (size_t)(k0 + brow) * 64 + bcol);

        __syncthreads();
        AsT[ak + 0][arow] = av.x;
        AsT[ak + 1][arow] = av.y;
        AsT[ak + 2][arow] = av.z;
        AsT[ak + 3][arow] = av.w;
        *(float4*)&Bs[brow][bcol] = bv;
        __syncthreads();

#pragma unroll
        for (int kk = 0; kk < BK; ++kk) {
            float4 a = *(const float4*)&AsT[kk][ty * 4];
            float4 b = *(const float4*)&Bs [kk][tx * 4];
            acc[0][0] = fmaf(a.x, b.x, acc[0][0]);
            acc[0][1] = fmaf(a.x, b.y, acc[0][1]);
            acc[0][2] = fmaf(a.x, b.z, acc[0][2]);
            acc[0][3] = fmaf(a.x, b.w, acc[0][3]);
            acc[1][0] = fmaf(a.y, b.x, acc[1][0]);
            acc[1][1] = fmaf(a.y, b.y, acc[1][1]);
            acc[1][2] = fmaf(a.y, b.z, acc[1][2]);
            acc[1][3] = fmaf(a.y, b.w, acc[1][3]);
            acc[2][0] = fmaf(a.z, b.x, acc[2][0]);
            acc[2][1] = fmaf(a.z, b.y, acc[2][1]);
            acc[2][2] = fmaf(a.z, b.z, acc[2][2]);
            acc[2][3] = fmaf(a.z, b.w, acc[2][3]);
            acc[3][0] = fmaf(a.w, b.x, acc[3][0]);
            acc[3][1] = fmaf(a.w, b.y, acc[3][1]);
            acc[3][2] = fmaf(a.w, b.z, acc[3][2]);
            acc[3][3] = fmaf(a.w, b.w, acc[3][3]);
        }
    }

#pragma unroll
    for (int i = 0; i < 4; ++i) {
        int r = rowBase + ty * 4 + i;
        if (r < nrows) {
            float4 o;
            o.x = acc[i][0]; o.y = acc[i][1]; o.z = acc[i][2]; o.w = acc[i][3];
            if (RELU) {
                o.x = fmaxf(o.x, 0.f); o.y = fmaxf(o.y, 0.f);
                o.z = fmaxf(o.z, 0.f); o.w = fmaxf(o.w, 0.f);
            }
            *(float4*)(C + (size_t)r * 64 + tx * 4) = o;
        }
    }
}

// ---------------------------------------------------------------------------
// GEMM2 with fused epilogue: emits bf16(z0) (propagation seed) and
// bf16(ALPHA*z0) directly; fp32 z0 never hits memory, cvt kernel deleted.
// ---------------------------------------------------------------------------
__global__ __launch_bounds__(256) void gemm2_kernel(
    const float* __restrict__ A, const float* __restrict__ B,
    ushort_t* __restrict__ zb, ushort_t* __restrict__ az, int nrows, int K)
{
    const int BK = 16;
    __shared__ float AsT[BK][68];
    __shared__ float Bs [BK][68];

    int tid = threadIdx.x;
    int tx  = tid & 15;
    int ty  = tid >> 4;
    int rowBase = blockIdx.x * 64;

    int arow = tid >> 2;
    int ak   = (tid & 3) * 4;
    int brow = tid >> 4;
    int bcol = (tid & 15) * 4;

    float acc[4][4] = {};

    for (int k0 = 0; k0 < K; k0 += BK) {
        float4 av;
        int gr = rowBase + arow;
        if (gr < nrows) av = *(const float4*)(A + (size_t)gr * K + k0 + ak);
        else            av = make_float4(0.f, 0.f, 0.f, 0.f);
        float4 bv = *(const float4*)(B + (size_t)(k0 + brow) * 64 + bcol);

        __syncthreads();
        AsT[ak + 0][arow] = av.x;
        AsT[ak + 1][arow] = av.y;
        AsT[ak + 2][arow] = av.z;
        AsT[ak + 3][arow] = av.w;
        *(float4*)&Bs[brow][bcol] = bv;
        __syncthreads();

#pragma unroll
        for (int kk = 0; kk < BK; ++kk) {
            float4 a = *(const float4*)&AsT[kk][ty * 4];
            float4 b = *(const float4*)&Bs [kk][tx * 4];
            acc[0][0] = fmaf(a.x, b.x, acc[0][0]);
            acc[0][1] = fmaf(a.x, b.y, acc[0][1]);
            acc[0][2] = fmaf(a.x, b.z, acc[0][2]);
            acc[0][3] = fmaf(a.x, b.w, acc[0][3]);
            acc[1][0] = fmaf(a.y, b.x, acc[1][0]);
            acc[1][1] = fmaf(a.y, b.y, acc[1][1]);
            acc[1][2] = fmaf(a.y, b.z, acc[1][2]);
            acc[1][3] = fmaf(a.y, b.w, acc[1][3]);
            acc[2][0] = fmaf(a.z, b.x, acc[2][0]);
            acc[2][1] = fmaf(a.z, b.y, acc[2][1]);
            acc[2][2] = fmaf(a.z, b.z, acc[2][2]);
            acc[2][3] = fmaf(a.z, b.w, acc[2][3]);
            acc[3][0] = fmaf(a.w, b.x, acc[3][0]);
            acc[3][1] = fmaf(a.w, b.y, acc[3][1]);
            acc[3][2] = fmaf(a.w, b.z, acc[3][2]);
            acc[3][3] = fmaf(a.w, b.w, acc[3][3]);
        }
    }

#pragma unroll
    for (int i = 0; i < 4; ++i) {
        int r = rowBase + ty * 4 + i;
        if (r < nrows) {
            ushort4 o, oa;
            o.x  = f2bf(acc[i][0]);         o.y  = f2bf(acc[i][1]);
            o.z  = f2bf(acc[i][2]);         o.w  = f2bf(acc[i][3]);
            oa.x = f2bf(ALPHA * acc[i][0]); oa.y = f2bf(ALPHA * acc[i][1]);
            oa.z = f2bf(ALPHA * acc[i][2]); oa.w = f2bf(ALPHA * acc[i][3]);
            *(ushort4*)(zb + (size_t)r * 64 + tx * 4) = o;
            *(ushort4*)(az + (size_t)r * 64 + tx * 4) = oa;
        }
    }
}

// ---------------------------------------------------------------------------
// CSR construction (per-node cursors, low contention)
// ---------------------------------------------------------------------------
__global__ __launch_bounds__(256) void zero_kernel(int* __restrict__ p, int n)
{
    int i = blockIdx.x * 256 + threadIdx.x;
    if (i < n) p[i] = 0;
}

__global__ __launch_bounds__(256) void count_kernel(const int* __restrict__ dst,
                                                    int* __restrict__ deg)
{
    int e = blockIdx.x * 256 + threadIdx.x;
    if (e < EE) atomicAdd(&deg[dst[e]], 1);
}

__global__ __launch_bounds__(256) void scanA_kernel(const int* __restrict__ deg,
                                                    int* __restrict__ bsum)
{
    int b = blockIdx.x, t = threadIdx.x;
    int i = b * CHUNK + t * 2;
    int v = 0;
    if (i < NN)     v += deg[i];
    if (i + 1 < NN) v += deg[i + 1];
    __shared__ int sm[256];
    sm[t] = v;
    __syncthreads();
    for (int o = 128; o > 0; o >>= 1) {
        if (t < o) sm[t] += sm[t + o];
        __syncthreads();
    }
    if (t == 0) bsum[b] = sm[0];
}

__global__ __launch_bounds__(256) void scanB_kernel(const int* __restrict__ bsum,
                                                    int* __restrict__ bbase,
                                                    int* __restrict__ offs)
{
    int t = threadIdx.x;
    int v = (t < NB) ? bsum[t] : 0;
    __shared__ int sm[256];
    sm[t] = v;
    __syncthreads();
    for (int o = 1; o < 256; o <<= 1) {
        int u = (t >= o) ? sm[t - o] : 0;
        __syncthreads();
        sm[t] += u;
        __syncthreads();
    }
    if (t < NB) bbase[t] = sm[t] - v;
    if (t == 0) offs[NN] = EE;
}

__global__ __launch_bounds__(256) void scanC_kernel(const int* __restrict__ deg,
                                                    const int* __restrict__ bbase,
                                                    int* __restrict__ offs,
                                                    int* __restrict__ cursor)
{
    int b = blockIdx.x, t = threadIdx.x;
    int i0 = b * CHUNK + t * 2;
    int d0 = (i0 < NN)     ? deg[i0]     : 0;
    int d1 = (i0 + 1 < NN) ? deg[i0 + 1] : 0;
    int local = d0 + d1;
    __shared__ int sm[256];
    sm[t] = local;
    __syncthreads();
    for (int o = 1; o < 256; o <<= 1) {
        int u = (t >= o) ? sm[t - o] : 0;
        __syncthreads();
        sm[t] += u;
        __syncthreads();
    }
    int excl = sm[t] - local + bbase[b];
    if (i0 < NN)     { offs[i0]     = excl;      cursor[i0]     = excl;      }
    if (i0 + 1 < NN) { offs[i0 + 1] = excl + d0; cursor[i0 + 1] = excl + d0; }
}

// ---------------------------------------------------------------------------
// XCD-partitioned scatter. 2048 persistent blocks are all co-resident, so the
// round-robin blockIdx%8 -> XCD mapping holds for the kernel lifetime. Block
// group x only writes edges with dst in its 1/8 node range; each XCD's 3.2MB
// CSR segment then assembles full 64B lines in its own L2 before writeback
// (kills the measured 8x write amplification: 198.8MB -> ~26MB).
// Correctness is independent of the XCD mapping (pure dst-range filter).
// ---------------------------------------------------------------------------
__global__ __launch_bounds__(256) void scatter_kernel(
    const int* __restrict__ src, const int* __restrict__ dst,
    const float* __restrict__ w, int* cursor, int2* __restrict__ csr)
{
    const int x      = blockIdx.x & 7;
    const int lo     = x * (NN / 8);          // NN/8 = 12500 exact
    const int hi     = lo + (NN / 8);
    const int nsl    = gridDim.x >> 3;
    const int stride = nsl * 256;
    for (int e = (blockIdx.x >> 3) * 256 + threadIdx.x; e < EE; e += stride) {
        int d = dst[e];
        if (d >= lo && d < hi) {
            int pos = atomicAdd(&cursor[d], 1);
            csr[pos] = make_int2(src[e], __float_as_int(w[e]));
        }
    }
}

// ---------------------------------------------------------------------------
// APPNP propagation: one wave per dst node, lane = class. bf16 z, fp32 acc.
// csr stream is nt-loaded and zout nt-stored so the 12.8MB zin gather table
// keeps per-XCD L2 residency. alpha*z0 comes pre-scaled in bf16 (az0).
// ---------------------------------------------------------------------------
template <bool LSM>
__global__ __launch_bounds__(256) void propagate_kernel(
    const ushort_t* __restrict__ zin, const ushort_t* __restrict__ az0,
    ushort_t* __restrict__ zout_b, float* __restrict__ zout_f,
    const int* __restrict__ offs, const int2* __restrict__ csr)
{
    int gid  = blockIdx.x * 256 + threadIdx.x;
    int node = gid >> 6;
    int lane = gid & 63;
    if (node >= NN) return;

    int beg = offs[node];
    int end = offs[node + 1];
    float acc = 0.f;
    int j = beg;
    for (; j + 8 <= end; j += 8) {
        int2 e0 = ldnt_e(csr + j);     int2 e1 = ldnt_e(csr + j + 1);
        int2 e2 = ldnt_e(csr + j + 2); int2 e3 = ldnt_e(csr + j + 3);
        int2 e4 = ldnt_e(csr + j + 4); int2 e5 = ldnt_e(csr + j + 5);
        int2 e6 = ldnt_e(csr + j + 6); int2 e7 = ldnt_e(csr + j + 7);
        float v0 = bf2f(zin[(size_t)e0.x * 64 + lane]);
        float v1 = bf2f(zin[(size_t)e1.x * 64 + lane]);
        float v2 = bf2f(zin[(size_t)e2.x * 64 + lane]);
        float v3 = bf2f(zin[(size_t)e3.x * 64 + lane]);
        float v4 = bf2f(zin[(size_t)e4.x * 64 + lane]);
        float v5 = bf2f(zin[(size_t)e5.x * 64 + lane]);
        float v6 = bf2f(zin[(size_t)e6.x * 64 + lane]);
        float v7 = bf2f(zin[(size_t)e7.x * 64 + lane]);
        acc = fmaf(__int_as_float(e0.y), v0, acc);
        acc = fmaf(__int_as_float(e1.y), v1, acc);
        acc = fmaf(__int_as_float(e2.y), v2, acc);
        acc = fmaf(__int_as_float(e3.y), v3, acc);
        acc = fmaf(__int_as_float(e4.y), v4, acc);
        acc = fmaf(__int_as_float(e5.y), v5, acc);
        acc = fmaf(__int_as_float(e6.y), v6, acc);
        acc = fmaf(__int_as_float(e7.y), v7, acc);
    }
    for (; j < end; ++j) {
        int2 e = ldnt_e(csr + j);
        acc = fmaf(__int_as_float(e.y), bf2f(zin[(size_t)e.x * 64 + lane]), acc);
    }

    float out = acc + bf2f(az0[(size_t)node * 64 + lane]);

    if (LSM) {
        float m = out;
#pragma unroll
        for (int o = 32; o > 0; o >>= 1) m = fmaxf(m, __shfl_xor(m, o, 64));
        float e = __expf(out - m);
        float s = e;
#pragma unroll
        for (int o = 32; o > 0; o >>= 1) s += __shfl_xor(s, o, 64);
        __builtin_nontemporal_store((out - m) - __logf(s),
                                    zout_f + (size_t)node * 64 + lane);
    } else {
        __builtin_nontemporal_store(f2bf(out),
                                    zout_b + (size_t)node * 64 + lane);
    }
}

// ---------------------------------------------------------------------------
extern "C" void kernel_launch(void* const* d_in, const int* in_sizes, int n_in,
                              void* d_out, int out_size, void* d_ws, size_t ws_size,
                              hipStream_t stream)
{
    const float* x  = (const float*)d_in[0];
    const int*   ei = (const int*)  d_in[1];
    const float* ew = (const float*)d_in[2];
    const float* W1 = (const float*)d_in[3];
    const float* W2 = (const float*)d_in[4];
    const int* src = ei;
    const int* dst = ei + EE;

    char* ws = (char*)d_ws;
    size_t off = 0;
    auto alloc = [&](size_t bytes) -> char* {
        char* p = ws + off;
        off += (bytes + 255) & ~(size_t)255;
        return p;
    };

    float*    h     = (float*)   alloc((size_t)NN * HIDN * 4);  // 25.6 MB; -> csr
    ushort_t* zbA   = (ushort_t*)alloc((size_t)NN * NCLS * 2);  // 12.8 MB (bf16 z0 seed)
    ushort_t* zbB   = (ushort_t*)alloc((size_t)NN * NCLS * 2);  // 12.8 MB
    ushort_t* az0   = (ushort_t*)alloc((size_t)NN * NCLS * 2);  // 12.8 MB (bf16 alpha*z0)
    int*      deg   = (int*)     alloc((size_t)NN * 4);
    int*      offs  = (int*)     alloc((size_t)(NN + 1) * 4);
    int*      cur_  = (int*)     alloc((size_t)NN * 4);
    int*      bsum  = (int*)     alloc((size_t)NB * 4);
    int*      bbase = (int*)     alloc((size_t)NB * 4);

    int2* csr = (int2*)h;       // h dead after GEMM2

    // feature transform (gemm2 fuses z0->bf16 + alpha*z0->bf16 epilogue)
    gemm_kernel<true><<<(NN + 63) / 64, 256, 0, stream>>>(x, W1, h, NN, NF);
    gemm2_kernel<<<(NN + 63) / 64, 256, 0, stream>>>(h, W2, zbA, az0, NN, HIDN);

    // CSR build
    zero_kernel<<<(NN + 255) / 256, 256, 0, stream>>>(deg, NN);
    count_kernel<<<EE / 256, 256, 0, stream>>>(dst, deg);
    scanA_kernel<<<NB, 256, 0, stream>>>(deg, bsum);
    scanB_kernel<<<1, 256, 0, stream>>>(bsum, bbase, offs);
    scanC_kernel<<<NB, 256, 0, stream>>>(deg, bbase, offs, cur_);
    scatter_kernel<<<SC_BLOCKS, 256, 0, stream>>>(src, dst, ew, cur_, csr);

    // 10 power iterations, bf16 ping-pong; final emits fp32 log_softmax
    const ushort_t* cur = zbA;
    ushort_t* nxt = zbB;
    for (int it = 0; it < 9; ++it) {
        propagate_kernel<false><<<(NN * 64) / 256, 256, 0, stream>>>(
            cur, az0, nxt, nullptr, offs, csr);
        ushort_t* t = (ushort_t*)cur; cur = nxt; nxt = t;
    }
    propagate_kernel<true><<<(NN * 64) / 256, 256, 0, stream>>>(
        cur, az0, nullptr, (float*)d_out, offs, csr);
}